// Round 1
// baseline (476.259 us; speedup 1.0000x reference)
//
#include <hip/hip_runtime.h>
#include <cstdint>
#include <cstddef>

#define B 64
#define S 2048
#define D 512
#define H 128
#define Q 4
#define QH 32
#define KTOP 4
#define NROWS (B * S)
#define NEGV -1e9f

// ---------------------------------------------------------------------------
// Kernel 0: detect mask dtype from raw bytes (bool arrays may arrive as u8,
// i32, i64, f32 or f64 depending on harness conversion).
// modes: 0=u8, 1=i32, 2=i64, 3=f32, 4=f64
// ---------------------------------------------------------------------------
__global__ void detect_mask_kernel(const unsigned char* __restrict__ m, int* __restrict__ mode) {
    __shared__ int fF0, fF, fB, fO4;
    if (threadIdx.x == 0) { fF0 = 0; fF = 0; fB = 0; fO4 = 0; }
    __syncthreads();
    int a = 0, bb = 0, c = 0, d = 0;
    for (int i = threadIdx.x; i < NROWS; i += 256) {
        unsigned char x = m[i];
        if (x == 0xF0) a = 1;                 // f64 mantissa-top byte of 1.0
        if (x == 0x3F || x == 0x80) bb = 1;   // f32 bytes of 1.0f
        if ((i & 3) && x) c = 1;              // u8: 0/1 everywhere
        if (((i & 7) == 4) && x) d = 1;       // i32: odd elements' low byte
    }
    if (a) atomicOr(&fF0, 1);
    if (bb) atomicOr(&fF, 1);
    if (c) atomicOr(&fB, 1);
    if (d) atomicOr(&fO4, 1);
    __syncthreads();
    if (threadIdx.x == 0) {
        int md;
        if (fF0) md = 4;
        else if (fF) md = 3;
        else if (fB) md = 0;
        else if (fO4) md = 1;
        else md = 2;
        *mode = md;
    }
}

// ---------------------------------------------------------------------------
// Kernel 1: expand mask to float + quality MLP (relu) per (b,s)
// ---------------------------------------------------------------------------
__global__ __launch_bounds__(256) void prep_kernel(
    const void* __restrict__ mraw, const float* __restrict__ segq,
    const float* __restrict__ qW1, const float* __restrict__ qb1,
    const float* __restrict__ qw2, const float* __restrict__ qb2,
    const int* __restrict__ mode, float* __restrict__ maskf, float* __restrict__ qual) {
    __shared__ float sW[Q * QH];
    __shared__ float sb1[QH];
    __shared__ float sw2[QH];
    __shared__ float sb2v;
    const int t = threadIdx.x;
    if (t < Q * QH) sW[t] = qW1[t];
    if (t >= 128 && t < 128 + QH) sb1[t - 128] = qb1[t - 128];
    if (t >= 160 && t < 160 + QH) sw2[t - 160] = qw2[t - 160];
    if (t == 192) sb2v = qb2[0];
    __syncthreads();

    const int i = blockIdx.x * 256 + t;
    const int md = *mode;
    float mv;
    switch (md) {
        case 0: mv = ((const unsigned char*)mraw)[i] ? 1.f : 0.f; break;
        case 1: mv = ((const int*)mraw)[i] ? 1.f : 0.f; break;
        case 2: mv = ((const long long*)mraw)[i] ? 1.f : 0.f; break;
        case 3: mv = (((const float*)mraw)[i] != 0.f) ? 1.f : 0.f; break;
        default: mv = (((const double*)mraw)[i] != 0.0) ? 1.f : 0.f; break;
    }
    maskf[i] = mv;

    float4 sq = *reinterpret_cast<const float4*>(&segq[(size_t)i * Q]);
    float s = 0.f;
#pragma unroll
    for (int h = 0; h < QH; ++h) {
        float a = sq.x * sW[h] + sq.y * sW[QH + h] + sq.z * sW[2 * QH + h] + sq.w * sW[3 * QH + h] + sb1[h];
        a = fmaxf(a, 0.f);
        s += a * sw2[h];
    }
    qual[i] = s + sb2v;
}

// ---------------------------------------------------------------------------
// Kernel 2: evidence = tanh(X*W1 + b1) @ w2 + b2; write masked combined logits
// Tile: 64 rows x 128 h, BK=64. 256 thr, thread owns 4 rows x 8 h (32 acc).
// ---------------------------------------------------------------------------
#define TM 64
#define BK 64
#define SASTR (BK + 4)

__global__ __launch_bounds__(256) void evidence_kernel(
    const float* __restrict__ feats, const float* __restrict__ W1,
    const float* __restrict__ b1g, const float* __restrict__ w2g,
    const float* __restrict__ b2g, const float* __restrict__ qual,
    const float* __restrict__ maskf, float* __restrict__ comb) {
    __shared__ float sA[TM * SASTR];  // feats tile [r][k], pad 4
    __shared__ float sB[BK * H];      // W1 tile [k][h]
    const int t = threadIdx.x;
    const int row0 = blockIdx.x * TM;
    const int h0 = (t & 15) * 8;
    const int r0 = (t >> 4) * 4;

    float acc[4][8];
#pragma unroll
    for (int i = 0; i < 4; ++i)
#pragma unroll
        for (int j = 0; j < 8; ++j) acc[i][j] = 0.f;

    for (int kc = 0; kc < D; kc += BK) {
#pragma unroll
        for (int p = 0; p < 4; ++p) {
            int idx = p * 256 + t;      // 1024 float4 loads
            int r = idx >> 4;
            int c = (idx & 15) << 2;
            float4 v = *reinterpret_cast<const float4*>(&feats[(size_t)(row0 + r) * D + kc + c]);
            *reinterpret_cast<float4*>(&sA[r * SASTR + c]) = v;
        }
#pragma unroll
        for (int p = 0; p < 8; ++p) {
            int idx = p * 256 + t;      // 2048 float4 loads
            int kk = idx >> 5;
            int hh = (idx & 31) << 2;
            float4 v = *reinterpret_cast<const float4*>(&W1[(size_t)(kc + kk) * H + hh]);
            *reinterpret_cast<float4*>(&sB[kk * H + hh]) = v;
        }
        __syncthreads();
#pragma unroll 8
        for (int k = 0; k < BK; ++k) {
            float a[4];
#pragma unroll
            for (int i = 0; i < 4; ++i) a[i] = sA[(r0 + i) * SASTR + k];
            float4 bv0 = *reinterpret_cast<const float4*>(&sB[k * H + h0]);
            float4 bv1 = *reinterpret_cast<const float4*>(&sB[k * H + h0 + 4]);
            float bbv[8] = {bv0.x, bv0.y, bv0.z, bv0.w, bv1.x, bv1.y, bv1.z, bv1.w};
#pragma unroll
            for (int i = 0; i < 4; ++i)
#pragma unroll
                for (int j = 0; j < 8; ++j) acc[i][j] = fmaf(a[i], bbv[j], acc[i][j]);
        }
        __syncthreads();
    }

    // tanh + dot w2 partials, reduce across the 16 h-groups
    float pr[4];
#pragma unroll
    for (int i = 0; i < 4; ++i) {
        float s = 0.f;
#pragma unroll
        for (int j = 0; j < 8; ++j) s += tanhf(acc[i][j] + b1g[h0 + j]) * w2g[h0 + j];
        pr[i] = s;
    }
    float* red = sA;  // reuse, [TM][17]
    const int hg = t & 15;
#pragma unroll
    for (int i = 0; i < 4; ++i) red[(r0 + i) * 17 + hg] = pr[i];
    __syncthreads();
    if (t < TM) {
        float e = b2g[0];
#pragma unroll
        for (int g = 0; g < 16; ++g) e += red[t * 17 + g];
        int row = row0 + t;
        comb[row] = (maskf[row] != 0.f) ? (e + qual[row]) : NEGV;
    }
}

// ---------------------------------------------------------------------------
// Kernel 3: per-row masked softmax (writes weights) + top-4 (tie: lower index)
// one block of 256 threads per row b
// ---------------------------------------------------------------------------
__global__ __launch_bounds__(256) void softmax_topk_kernel(
    const float* __restrict__ comb, float* __restrict__ o_weights,
    float* __restrict__ o_tidx, float* __restrict__ o_tval,
    int* __restrict__ tidx_ws, int* __restrict__ tval_ws, float* __restrict__ denom_ws) {
    __shared__ float sc[S];
    __shared__ float rbuf[4];
    __shared__ float mvv[256 * 4];
    __shared__ int mii[256 * 4];
    const int b = blockIdx.x, t = threadIdx.x;
    const float* row = comb + (size_t)b * S;

    float lmax = -3e38f;
    for (int s = t; s < S; s += 256) {
        float v = row[s];
        sc[s] = v;
        lmax = fmaxf(lmax, v);
    }
#pragma unroll
    for (int o = 32; o > 0; o >>= 1) lmax = fmaxf(lmax, __shfl_xor(lmax, o, 64));
    if ((t & 63) == 0) rbuf[t >> 6] = lmax;
    __syncthreads();
    const float m = fmaxf(fmaxf(rbuf[0], rbuf[1]), fmaxf(rbuf[2], rbuf[3]));

    float lsum = 0.f;
    for (int s = t; s < S; s += 256) {
        float v = sc[s];
        float e = (v > -1e8f) ? __expf(v - m) : 0.f;
        o_weights[(size_t)b * S + s] = e;
        lsum += e;
    }
#pragma unroll
    for (int o = 32; o > 0; o >>= 1) lsum += __shfl_xor(lsum, o, 64);
    __syncthreads();  // rbuf reuse
    if ((t & 63) == 0) rbuf[t >> 6] = lsum;
    __syncthreads();
    const float sum = rbuf[0] + rbuf[1] + rbuf[2] + rbuf[3];
    const float inv = 1.f / fmaxf(sum, 1e-8f);
    for (int s = t; s < S; s += 256) o_weights[(size_t)b * S + s] *= inv;

    // ---- top-4 ----
    float tv[4] = {-3e38f, -3e38f, -3e38f, -3e38f};
    int ti[4] = {1 << 30, 1 << 30, 1 << 30, 1 << 30};
    for (int s = t; s < S; s += 256) {
        float v = sc[s];
        if (v > tv[3]) {  // strict: within a thread s ascends, ties keep earlier
            tv[3] = v; ti[3] = s;
#pragma unroll
            for (int k = 3; k > 0; --k) {
                bool up = (tv[k] > tv[k - 1]) || (tv[k] == tv[k - 1] && ti[k] < ti[k - 1]);
                if (up) {
                    float fv = tv[k]; tv[k] = tv[k - 1]; tv[k - 1] = fv;
                    int ii = ti[k]; ti[k] = ti[k - 1]; ti[k - 1] = ii;
                }
            }
        }
    }
#pragma unroll
    for (int k = 0; k < 4; ++k) { mvv[t * 4 + k] = tv[k]; mii[t * 4 + k] = ti[k]; }
    __syncthreads();
    for (int st = 128; st >= 1; st >>= 1) {
        if (t < st) {
            float av[4], bv[4];
            int ai[4], bi[4];
#pragma unroll
            for (int k = 0; k < 4; ++k) {
                av[k] = mvv[t * 4 + k]; ai[k] = mii[t * 4 + k];
                bv[k] = mvv[(t + st) * 4 + k]; bi[k] = mii[(t + st) * 4 + k];
            }
            float rv[4]; int ri[4];
            int i = 0, j = 0;
            for (int o = 0; o < 4; ++o) {
                bool ta = (av[i] > bv[j]) || (av[i] == bv[j] && ai[i] < bi[j]);
                if (ta) { rv[o] = av[i]; ri[o] = ai[i]; ++i; }
                else { rv[o] = bv[j]; ri[o] = bi[j]; ++j; }
            }
#pragma unroll
            for (int k = 0; k < 4; ++k) { mvv[t * 4 + k] = rv[k]; mii[t * 4 + k] = ri[k]; }
        }
        __syncthreads();
    }
    if (t == 0) {
        float dn = 0.f;
#pragma unroll
        for (int k = 0; k < 4; ++k) {
            int idx = mii[k];
            int valid = (mvv[k] > -1e8f) ? 1 : 0;
            tidx_ws[b * 4 + k] = idx;
            tval_ws[b * 4 + k] = valid;
            o_tidx[b * 4 + k] = (float)idx;
            o_tval[b * 4 + k] = (float)valid;
            dn += (float)valid;
        }
        denom_ws[b] = fmaxf(dn, 1.f);
    }
}

// ---------------------------------------------------------------------------
// Kernel 4: partial attention pooling. grid (16 s-chunks, 64 b), 256 thr
// ---------------------------------------------------------------------------
__global__ __launch_bounds__(256) void pool_partial_kernel(
    const float* __restrict__ feats, const float* __restrict__ wts, float* __restrict__ part) {
    const int b = blockIdx.y, ch = blockIdx.x, t = threadIdx.x;
    const int SC = S / 16;  // 128
    const int s0 = ch * SC;
    __shared__ float sw[S / 16];
    if (t < SC) sw[t] = wts[(size_t)b * S + s0 + t];
    __syncthreads();
    float a0 = 0.f, a1 = 0.f;
    const float* fp = feats + ((size_t)b * S + s0) * D + t * 2;
#pragma unroll 4
    for (int s = 0; s < SC; ++s) {
        float wv = sw[s];
        if (wv != 0.f) {  // wave-uniform branch; skip masked rows (~30% BW)
            float2 f = *reinterpret_cast<const float2*>(fp);
            a0 += wv * f.x;
            a1 += wv * f.y;
        }
        fp += D;
    }
    float* pp = &part[((size_t)(b * 16 + ch)) * D + t * 2];
    pp[0] = a0;
    pp[1] = a1;
}

// ---------------------------------------------------------------------------
// Kernel 5: reduce partials + top-k gather + mix. 64 blocks x 256 thr
// ---------------------------------------------------------------------------
__global__ __launch_bounds__(256) void pool_reduce_kernel(
    const float* __restrict__ part, const float* __restrict__ feats,
    const int* __restrict__ tidx, const int* __restrict__ tval,
    const float* __restrict__ denom, float* __restrict__ o_attn,
    float* __restrict__ o_topk, float* __restrict__ o_pooled) {
    const int b = blockIdx.x, t = threadIdx.x;
    const int i0 = tidx[b * 4 + 0], i1 = tidx[b * 4 + 1], i2 = tidx[b * 4 + 2], i3 = tidx[b * 4 + 3];
    const float v0 = tval[b * 4 + 0] ? 1.f : 0.f;
    const float v1 = tval[b * 4 + 1] ? 1.f : 0.f;
    const float v2 = tval[b * 4 + 2] ? 1.f : 0.f;
    const float v3 = tval[b * 4 + 3] ? 1.f : 0.f;
    const float inv_dn = 1.f / denom[b];
    for (int d = t; d < D; d += 256) {
        float s = 0.f;
#pragma unroll
        for (int ch = 0; ch < 16; ++ch) s += part[((size_t)(b * 16 + ch)) * D + d];
        float tk = v0 * feats[((size_t)b * S + i0) * D + d] + v1 * feats[((size_t)b * S + i1) * D + d] +
                   v2 * feats[((size_t)b * S + i2) * D + d] + v3 * feats[((size_t)b * S + i3) * D + d];
        tk *= inv_dn;
        o_attn[(size_t)b * D + d] = s;
        o_topk[(size_t)b * D + d] = tk;
        o_pooled[(size_t)b * D + d] = 0.5f * s + 0.5f * tk;
    }
}

// ---------------------------------------------------------------------------
extern "C" void kernel_launch(void* const* d_in, const int* in_sizes, int n_in,
                              void* d_out, int out_size, void* d_ws, size_t ws_size,
                              hipStream_t stream) {
    const float* feats = (const float*)d_in[0];
    const void* maskraw = d_in[1];
    const float* segq = (const float*)d_in[2];
    const float* W1 = (const float*)d_in[3];
    const float* b1 = (const float*)d_in[4];
    const float* w2 = (const float*)d_in[5];
    const float* b2 = (const float*)d_in[6];
    const float* qW1 = (const float*)d_in[7];
    const float* qb1 = (const float*)d_in[8];
    const float* qw2 = (const float*)d_in[9];
    const float* qb2 = (const float*)d_in[10];

    char* ws = (char*)d_ws;
    int* mode = (int*)ws;                       // 16 B reserved
    float* maskf = (float*)(ws + 16);           // B*S
    float* qual = maskf + NROWS;                // B*S
    float* comb = qual + NROWS;                 // B*S
    float* part = comb + NROWS;                 // B*16*D
    int* tidx_ws = (int*)(part + (size_t)B * 16 * D);
    int* tval_ws = tidx_ws + B * KTOP;
    float* denom_ws = (float*)(tval_ws + B * KTOP);

    float* out = (float*)d_out;
    float* o_pooled = out;                       // B*D
    float* o_weights = out + (size_t)B * D;      // B*S
    float* o_attn = o_weights + (size_t)B * S;   // B*D
    float* o_topk = o_attn + (size_t)B * D;      // B*D
    float* o_tidx = o_topk + (size_t)B * D;      // B*K
    float* o_tval = o_tidx + (size_t)B * KTOP;   // B*K

    detect_mask_kernel<<<1, 256, 0, stream>>>((const unsigned char*)maskraw, mode);
    prep_kernel<<<NROWS / 256, 256, 0, stream>>>(maskraw, segq, qW1, qb1, qw2, qb2, mode, maskf, qual);
    evidence_kernel<<<NROWS / TM, 256, 0, stream>>>(feats, W1, b1, w2, b2, qual, maskf, comb);
    softmax_topk_kernel<<<B, 256, 0, stream>>>(comb, o_weights, o_tidx, o_tval, tidx_ws, tval_ws, denom_ws);
    pool_partial_kernel<<<dim3(16, B), 256, 0, stream>>>(feats, o_weights, part);
    pool_reduce_kernel<<<B, 256, 0, stream>>>(part, feats, tidx_ws, tval_ws, denom_ws, o_attn, o_topk, o_pooled);
}

// Round 2
// 143.648 us; speedup vs baseline: 3.3154x; 3.3154x over previous
//
#include <hip/hip_runtime.h>
#include <cstdint>
#include <cstddef>

#define B 64
#define S 2048
#define D 512
#define H 128
#define Q 4
#define QH 32
#define KTOP 4
#define NROWS (B * S)
#define NEGV -1e9f
#define NCH 32
#define SC (S / NCH)

typedef __bf16 bf16x8 __attribute__((ext_vector_type(8)));
typedef float f32x4 __attribute__((ext_vector_type(4)));
typedef unsigned short us8 __attribute__((ext_vector_type(8)));

// ---------------------------------------------------------------------------
// Kernel 0: detect mask dtype from raw bytes (vectorized uint4 + SWAR).
// modes: 0=u8, 1=i32, 2=i64, 3=f32, 4=f64
// ---------------------------------------------------------------------------
__device__ __forceinline__ unsigned hasbyte(unsigned v, unsigned c) {
    unsigned x = v ^ (c * 0x01010101u);
    return (x - 0x01010101u) & ~x & 0x80808080u;
}

__global__ void detect_mask_kernel(const unsigned char* __restrict__ m, int* __restrict__ mode) {
    __shared__ int fF0, fF, fB, fO4;
    if (threadIdx.x == 0) { fF0 = 0; fF = 0; fB = 0; fO4 = 0; }
    __syncthreads();
    const uint4* mv = (const uint4*)m;
    int a = 0, bb = 0, c = 0, d = 0;
    for (int i = threadIdx.x; i < NROWS / 16; i += 256) {
        uint4 v = mv[i];
        // f64: byte 0xF0 anywhere (mantissa-top byte of 1.0)
        if (hasbyte(v.x, 0xF0u) | hasbyte(v.y, 0xF0u) | hasbyte(v.z, 0xF0u) | hasbyte(v.w, 0xF0u)) a = 1;
        // f32: bytes 0x3F or 0x80 anywhere (bytes of 1.0f)
        if (hasbyte(v.x, 0x3Fu) | hasbyte(v.y, 0x3Fu) | hasbyte(v.z, 0x3Fu) | hasbyte(v.w, 0x3Fu) |
            hasbyte(v.x, 0x80u) | hasbyte(v.y, 0x80u) | hasbyte(v.z, 0x80u) | hasbyte(v.w, 0x80u)) bb = 1;
        // u8: nonzero at byte pos where pos%4 != 0  (upper 3 bytes of each word)
        if ((v.x & 0xFFFFFF00u) | (v.y & 0xFFFFFF00u) | (v.z & 0xFFFFFF00u) | (v.w & 0xFFFFFF00u)) c = 1;
        // i32: nonzero at byte pos%8==4  (byte0 of odd words)
        if ((v.y & 0xFFu) | (v.w & 0xFFu)) d = 1;
    }
    if (a) atomicOr(&fF0, 1);
    if (bb) atomicOr(&fF, 1);
    if (c) atomicOr(&fB, 1);
    if (d) atomicOr(&fO4, 1);
    __syncthreads();
    if (threadIdx.x == 0) {
        int md;
        if (fF0) md = 4;
        else if (fF) md = 3;
        else if (fB) md = 0;
        else if (fO4) md = 1;
        else md = 2;
        *mode = md;
    }
}

// ---------------------------------------------------------------------------
// Kernel 1: expand mask to float + quality MLP (relu) per (b,s)
// ---------------------------------------------------------------------------
__global__ __launch_bounds__(256) void prep_kernel(
    const void* __restrict__ mraw, const float* __restrict__ segq,
    const float* __restrict__ qW1, const float* __restrict__ qb1,
    const float* __restrict__ qw2, const float* __restrict__ qb2,
    const int* __restrict__ mode, float* __restrict__ maskf, float* __restrict__ qual) {
    __shared__ float sW[Q * QH];
    __shared__ float sb1[QH];
    __shared__ float sw2[QH];
    __shared__ float sb2v;
    const int t = threadIdx.x;
    if (t < Q * QH) sW[t] = qW1[t];
    if (t >= 128 && t < 128 + QH) sb1[t - 128] = qb1[t - 128];
    if (t >= 160 && t < 160 + QH) sw2[t - 160] = qw2[t - 160];
    if (t == 192) sb2v = qb2[0];
    __syncthreads();

    const int i = blockIdx.x * 256 + t;
    const int md = *mode;
    float mv;
    switch (md) {
        case 0: mv = ((const unsigned char*)mraw)[i] ? 1.f : 0.f; break;
        case 1: mv = ((const int*)mraw)[i] ? 1.f : 0.f; break;
        case 2: mv = ((const long long*)mraw)[i] ? 1.f : 0.f; break;
        case 3: mv = (((const float*)mraw)[i] != 0.f) ? 1.f : 0.f; break;
        default: mv = (((const double*)mraw)[i] != 0.0) ? 1.f : 0.f; break;
    }
    maskf[i] = mv;

    float4 sq = *reinterpret_cast<const float4*>(&segq[(size_t)i * Q]);
    float s = 0.f;
#pragma unroll
    for (int h = 0; h < QH; ++h) {
        float a = sq.x * sW[h] + sq.y * sW[QH + h] + sq.z * sW[2 * QH + h] + sq.w * sW[3 * QH + h] + sb1[h];
        a = fmaxf(a, 0.f);
        s += a * sw2[h];
    }
    qual[i] = s + sb2v;
}

// ---------------------------------------------------------------------------
// Kernel 1b: split W1 [k=512][h=128] fp32 into transposed bf16 planes
// wsBh/wsBl layout: [h][k] (row-major k), so B-fragments are contiguous-k.
// ---------------------------------------------------------------------------
__device__ __forceinline__ void split_f32(float x, unsigned short& hi, unsigned short& lo) {
    unsigned bx = __float_as_uint(x);
    hi = (unsigned short)(bx >> 16);
    float fh = __uint_as_float(bx & 0xFFFF0000u);
    lo = (unsigned short)(__float_as_uint(x - fh) >> 16);
}

__global__ __launch_bounds__(256) void split_w1_kernel(
    const float* __restrict__ W1, unsigned short* __restrict__ bh, unsigned short* __restrict__ bl) {
    int i = blockIdx.x * 256 + threadIdx.x;  // i = h*512 + k
    int h = i >> 9, k = i & 511;
    float x = W1[(size_t)k * H + h];
    unsigned short hv, lv;
    split_f32(x, hv, lv);
    bh[i] = hv;
    bl[i] = lv;
}

// ---------------------------------------------------------------------------
// Kernel 2: evidence via split bf16 MFMA.
// C = feats(131072x512) * W1(512x128); per block: 128 rows x 128 h, BK=32.
// 4 waves in 2x2; wave tile 64x64 = 4x4 fragments of 16x16x32.
// 3 MFMA per fragment pair (hi*hi + hi*lo + lo*hi) ~ fp32 accuracy.
// Epilogue: tanh + dot(w2) + shuffle reduce -> comb logits (masked).
// ---------------------------------------------------------------------------
__device__ __forceinline__ float tanh_f(float x) {
    float e = __expf(2.f * x);
    return 1.f - __fdividef(2.f, e + 1.f);
}

__device__ __forceinline__ void gll16(const void* g, void* l) {
    __builtin_amdgcn_global_load_lds(
        (const __attribute__((address_space(1))) unsigned int*)g,
        (__attribute__((address_space(3))) unsigned int*)l, 16, 0, 0);
}

__global__ __launch_bounds__(256) void evidence_mfma_kernel(
    const float* __restrict__ feats, const unsigned short* __restrict__ wbh,
    const unsigned short* __restrict__ wbl, const float* __restrict__ b1g,
    const float* __restrict__ w2g, const float* __restrict__ b2g,
    const float* __restrict__ qual, const float* __restrict__ maskf,
    float* __restrict__ comb) {
    __shared__ unsigned short sAh[128][32];
    __shared__ unsigned short sAl[128][32];
    __shared__ unsigned short sBh[128][32];
    __shared__ unsigned short sBl[128][32];
    __shared__ float red[128][2];

    const int t = threadIdx.x;
    const int lane = t & 63;
    const int wid = t >> 6;
    const int wm = wid >> 1, wn = wid & 1;
    const int l16 = lane & 15, lk = lane >> 4;
    const int row0 = blockIdx.x * 128;

    f32x4 acc[4][4];
#pragma unroll
    for (int mf = 0; mf < 4; ++mf)
#pragma unroll
        for (int nf = 0; nf < 4; ++nf) acc[mf][nf] = (f32x4)0.f;

    // A staging map: thread -> (row r, k-half)
    const int ar = t >> 1;
    const int akh = (t & 1) * 16;
    const float* fsrc = feats + (size_t)(row0 + ar) * D + akh;

    // B staging map (global_load_lds, 2 calls per plane per wave):
    const int e0 = ((wid * 2 + 0) * 64 + lane) * 8;
    const int e1 = ((wid * 2 + 1) * 64 + lane) * 8;
    const int h0b = e0 >> 5, k0b = e0 & 31;
    const int h1b = e1 >> 5, k1b = e1 & 31;
    char* sBh0 = (char*)&sBh[0][0] + (wid * 2 + 0) * 1024;
    char* sBh1 = (char*)&sBh[0][0] + (wid * 2 + 1) * 1024;
    char* sBl0 = (char*)&sBl[0][0] + (wid * 2 + 0) * 1024;
    char* sBl1 = (char*)&sBl[0][0] + (wid * 2 + 1) * 1024;

    for (int kc = 0; kc < D; kc += 32) {
        // ---- stage B (async -> LDS) ----
        gll16(wbh + (size_t)h0b * D + kc + k0b, sBh0);
        gll16(wbh + (size_t)h1b * D + kc + k1b, sBh1);
        gll16(wbl + (size_t)h0b * D + kc + k0b, sBl0);
        gll16(wbl + (size_t)h1b * D + kc + k1b, sBl1);

        // ---- stage A: load 16 fp32, split to bf16 hi/lo ----
        float f[16];
        *reinterpret_cast<float4*>(&f[0]) = *reinterpret_cast<const float4*>(fsrc + kc + 0);
        *reinterpret_cast<float4*>(&f[4]) = *reinterpret_cast<const float4*>(fsrc + kc + 4);
        *reinterpret_cast<float4*>(&f[8]) = *reinterpret_cast<const float4*>(fsrc + kc + 8);
        *reinterpret_cast<float4*>(&f[12]) = *reinterpret_cast<const float4*>(fsrc + kc + 12);
        us8 vh0, vh1, vl0, vl1;
#pragma unroll
        for (int j = 0; j < 8; ++j) {
            unsigned short hh, ll;
            split_f32(f[j], hh, ll);
            vh0[j] = hh; vl0[j] = ll;
        }
#pragma unroll
        for (int j = 0; j < 8; ++j) {
            unsigned short hh, ll;
            split_f32(f[8 + j], hh, ll);
            vh1[j] = hh; vl1[j] = ll;
        }
        *reinterpret_cast<us8*>(&sAh[ar][akh]) = vh0;
        *reinterpret_cast<us8*>(&sAh[ar][akh + 8]) = vh1;
        *reinterpret_cast<us8*>(&sAl[ar][akh]) = vl0;
        *reinterpret_cast<us8*>(&sAl[ar][akh + 8]) = vl1;

        __syncthreads();

        // ---- fragments + MFMA ----
        bf16x8 ah[4], al[4], bh[4], bl[4];
#pragma unroll
        for (int mf = 0; mf < 4; ++mf) {
            int rr = wm * 64 + mf * 16 + l16;
            ah[mf] = *reinterpret_cast<const bf16x8*>(&sAh[rr][lk * 8]);
            al[mf] = *reinterpret_cast<const bf16x8*>(&sAl[rr][lk * 8]);
        }
#pragma unroll
        for (int nf = 0; nf < 4; ++nf) {
            int hh = wn * 64 + nf * 16 + l16;
            bh[nf] = *reinterpret_cast<const bf16x8*>(&sBh[hh][lk * 8]);
            bl[nf] = *reinterpret_cast<const bf16x8*>(&sBl[hh][lk * 8]);
        }
#pragma unroll
        for (int mf = 0; mf < 4; ++mf)
#pragma unroll
            for (int nf = 0; nf < 4; ++nf) {
                acc[mf][nf] = __builtin_amdgcn_mfma_f32_16x16x32_bf16(ah[mf], bh[nf], acc[mf][nf], 0, 0, 0);
                acc[mf][nf] = __builtin_amdgcn_mfma_f32_16x16x32_bf16(ah[mf], bl[nf], acc[mf][nf], 0, 0, 0);
                acc[mf][nf] = __builtin_amdgcn_mfma_f32_16x16x32_bf16(al[mf], bh[nf], acc[mf][nf], 0, 0, 0);
            }
        __syncthreads();
    }

    // ---- epilogue: tanh + w2 dot, reduce over 16 col-lanes ----
    float b1v[4], w2v[4];
#pragma unroll
    for (int nf = 0; nf < 4; ++nf) {
        int hh = wn * 64 + nf * 16 + l16;
        b1v[nf] = b1g[hh];
        w2v[nf] = w2g[hh];
    }
    float rs[4][4];
#pragma unroll
    for (int mf = 0; mf < 4; ++mf)
#pragma unroll
        for (int r2 = 0; r2 < 4; ++r2) {
            float s = 0.f;
#pragma unroll
            for (int nf = 0; nf < 4; ++nf) s += tanh_f(acc[mf][nf][r2] + b1v[nf]) * w2v[nf];
            s += __shfl_xor(s, 1, 16);
            s += __shfl_xor(s, 2, 16);
            s += __shfl_xor(s, 4, 16);
            s += __shfl_xor(s, 8, 16);
            rs[mf][r2] = s;
        }
    if (l16 == 0) {
#pragma unroll
        for (int mf = 0; mf < 4; ++mf)
#pragma unroll
            for (int r2 = 0; r2 < 4; ++r2) red[wm * 64 + mf * 16 + lk * 4 + r2][wn] = rs[mf][r2];
    }
    __syncthreads();
    if (t < 128) {
        int row = row0 + t;
        float e = red[t][0] + red[t][1] + b2g[0];
        comb[row] = (maskf[row] != 0.f) ? (e + qual[row]) : NEGV;
    }
}

// ---------------------------------------------------------------------------
// Kernel 3: per-row masked softmax (writes weights) + top-4 (tie: lower index)
// ---------------------------------------------------------------------------
__global__ __launch_bounds__(256) void softmax_topk_kernel(
    const float* __restrict__ comb, float* __restrict__ o_weights,
    float* __restrict__ o_tidx, float* __restrict__ o_tval,
    int* __restrict__ tidx_ws, int* __restrict__ tval_ws, float* __restrict__ denom_ws) {
    __shared__ float sc[S];
    __shared__ float rbuf[4];
    __shared__ float mvv[256 * 4];
    __shared__ int mii[256 * 4];
    const int b = blockIdx.x, t = threadIdx.x;
    const float* row = comb + (size_t)b * S;

    float lmax = -3e38f;
    for (int s = t; s < S; s += 256) {
        float v = row[s];
        sc[s] = v;
        lmax = fmaxf(lmax, v);
    }
#pragma unroll
    for (int o = 32; o > 0; o >>= 1) lmax = fmaxf(lmax, __shfl_xor(lmax, o, 64));
    if ((t & 63) == 0) rbuf[t >> 6] = lmax;
    __syncthreads();
    const float m = fmaxf(fmaxf(rbuf[0], rbuf[1]), fmaxf(rbuf[2], rbuf[3]));

    float lsum = 0.f;
    for (int s = t; s < S; s += 256) {
        float v = sc[s];
        float e = (v > -1e8f) ? __expf(v - m) : 0.f;
        o_weights[(size_t)b * S + s] = e;
        lsum += e;
    }
#pragma unroll
    for (int o = 32; o > 0; o >>= 1) lsum += __shfl_xor(lsum, o, 64);
    __syncthreads();
    if ((t & 63) == 0) rbuf[t >> 6] = lsum;
    __syncthreads();
    const float sum = rbuf[0] + rbuf[1] + rbuf[2] + rbuf[3];
    const float inv = 1.f / fmaxf(sum, 1e-8f);
    for (int s = t; s < S; s += 256) o_weights[(size_t)b * S + s] *= inv;

    // ---- top-4 ----
    float tv[4] = {-3e38f, -3e38f, -3e38f, -3e38f};
    int ti[4] = {1 << 30, 1 << 30, 1 << 30, 1 << 30};
    for (int s = t; s < S; s += 256) {
        float v = sc[s];
        if (v > tv[3]) {
            tv[3] = v; ti[3] = s;
#pragma unroll
            for (int k = 3; k > 0; --k) {
                bool up = (tv[k] > tv[k - 1]) || (tv[k] == tv[k - 1] && ti[k] < ti[k - 1]);
                if (up) {
                    float fv = tv[k]; tv[k] = tv[k - 1]; tv[k - 1] = fv;
                    int ii = ti[k]; ti[k] = ti[k - 1]; ti[k - 1] = ii;
                }
            }
        }
    }
#pragma unroll
    for (int k = 0; k < 4; ++k) { mvv[t * 4 + k] = tv[k]; mii[t * 4 + k] = ti[k]; }
    __syncthreads();
    for (int st = 128; st >= 1; st >>= 1) {
        if (t < st) {
            float av[4], bv[4];
            int ai[4], bi[4];
#pragma unroll
            for (int k = 0; k < 4; ++k) {
                av[k] = mvv[t * 4 + k]; ai[k] = mii[t * 4 + k];
                bv[k] = mvv[(t + st) * 4 + k]; bi[k] = mii[(t + st) * 4 + k];
            }
            float rv[4]; int ri[4];
            int i = 0, j = 0;
            for (int o = 0; o < 4; ++o) {
                bool ta = (av[i] > bv[j]) || (av[i] == bv[j] && ai[i] < bi[j]);
                if (ta) { rv[o] = av[i]; ri[o] = ai[i]; ++i; }
                else { rv[o] = bv[j]; ri[o] = bi[j]; ++j; }
            }
#pragma unroll
            for (int k = 0; k < 4; ++k) { mvv[t * 4 + k] = rv[k]; mii[t * 4 + k] = ri[k]; }
        }
        __syncthreads();
    }
    if (t == 0) {
        float dn = 0.f;
#pragma unroll
        for (int k = 0; k < 4; ++k) {
            int idx = mii[k];
            int valid = (mvv[k] > -1e8f) ? 1 : 0;
            tidx_ws[b * 4 + k] = idx;
            tval_ws[b * 4 + k] = valid;
            o_tidx[b * 4 + k] = (float)idx;
            o_tval[b * 4 + k] = (float)valid;
            dn += (float)valid;
        }
        denom_ws[b] = fmaxf(dn, 1.f);
    }
}

// ---------------------------------------------------------------------------
// Kernel 4: partial attention pooling, float4 lanes. grid (NCH, B), 256 thr
// ---------------------------------------------------------------------------
__global__ __launch_bounds__(256) void pool_partial_kernel(
    const float* __restrict__ feats, const float* __restrict__ wts, float* __restrict__ part) {
    const int b = blockIdx.y, ch = blockIdx.x, t = threadIdx.x;
    const int s0 = ch * SC;
    __shared__ float sw[SC];
    __shared__ float4 redp[256];
    if (t < SC) sw[t] = wts[(size_t)b * S + s0 + t];
    __syncthreads();
    const int dq = (t & 127) * 4;
    const int rp = t >> 7;
    float4 a = {0.f, 0.f, 0.f, 0.f};
    const float* fp = feats + ((size_t)b * S + s0 + rp) * D + dq;
    for (int s = rp; s < SC; s += 2) {
        float wv = sw[s];
        if (wv != 0.f) {  // wave-uniform (128-thread row groups)
            float4 f = *reinterpret_cast<const float4*>(fp);
            a.x += wv * f.x; a.y += wv * f.y; a.z += wv * f.z; a.w += wv * f.w;
        }
        fp += 2 * D;
    }
    redp[t] = a;
    __syncthreads();
    if (t < 128) {
        float4 o = redp[t], o2 = redp[t + 128];
        o.x += o2.x; o.y += o2.y; o.z += o2.z; o.w += o2.w;
        *reinterpret_cast<float4*>(&part[((size_t)(b * NCH + ch)) * D + dq]) = o;
    }
}

// ---------------------------------------------------------------------------
// Kernel 5: reduce partials + top-k gather + mix. 64 blocks x 256 thr
// ---------------------------------------------------------------------------
__global__ __launch_bounds__(256) void pool_reduce_kernel(
    const float* __restrict__ part, const float* __restrict__ feats,
    const int* __restrict__ tidx, const int* __restrict__ tval,
    const float* __restrict__ denom, float* __restrict__ o_attn,
    float* __restrict__ o_topk, float* __restrict__ o_pooled) {
    const int b = blockIdx.x, t = threadIdx.x;
    const int i0 = tidx[b * 4 + 0], i1 = tidx[b * 4 + 1], i2 = tidx[b * 4 + 2], i3 = tidx[b * 4 + 3];
    const float v0 = tval[b * 4 + 0] ? 1.f : 0.f;
    const float v1 = tval[b * 4 + 1] ? 1.f : 0.f;
    const float v2 = tval[b * 4 + 2] ? 1.f : 0.f;
    const float v3 = tval[b * 4 + 3] ? 1.f : 0.f;
    const float inv_dn = 1.f / denom[b];
    for (int d = t; d < D; d += 256) {
        float s = 0.f;
#pragma unroll
        for (int ch = 0; ch < NCH; ++ch) s += part[((size_t)(b * NCH + ch)) * D + d];
        float tk = v0 * feats[((size_t)b * S + i0) * D + d] + v1 * feats[((size_t)b * S + i1) * D + d] +
                   v2 * feats[((size_t)b * S + i2) * D + d] + v3 * feats[((size_t)b * S + i3) * D + d];
        tk *= inv_dn;
        o_attn[(size_t)b * D + d] = s;
        o_topk[(size_t)b * D + d] = tk;
        o_pooled[(size_t)b * D + d] = 0.5f * s + 0.5f * tk;
    }
}

// ---------------------------------------------------------------------------
extern "C" void kernel_launch(void* const* d_in, const int* in_sizes, int n_in,
                              void* d_out, int out_size, void* d_ws, size_t ws_size,
                              hipStream_t stream) {
    const float* feats = (const float*)d_in[0];
    const void* maskraw = d_in[1];
    const float* segq = (const float*)d_in[2];
    const float* W1 = (const float*)d_in[3];
    const float* b1 = (const float*)d_in[4];
    const float* w2 = (const float*)d_in[5];
    const float* b2 = (const float*)d_in[6];
    const float* qW1 = (const float*)d_in[7];
    const float* qb1 = (const float*)d_in[8];
    const float* qw2 = (const float*)d_in[9];
    const float* qb2 = (const float*)d_in[10];

    char* ws = (char*)d_ws;
    int* mode = (int*)ws;                        // 16 B reserved
    float* maskf = (float*)(ws + 16);            // B*S
    float* qual = maskf + NROWS;                 // B*S
    float* comb = qual + NROWS;                  // B*S
    float* part = comb + NROWS;                  // B*NCH*D (4 MiB)
    unsigned short* wsBh = (unsigned short*)(part + (size_t)B * NCH * D);  // 128*512
    unsigned short* wsBl = wsBh + (size_t)H * D;
    int* tidx_ws = (int*)(wsBl + (size_t)H * D);
    int* tval_ws = tidx_ws + B * KTOP;
    float* denom_ws = (float*)(tval_ws + B * KTOP);

    float* out = (float*)d_out;
    float* o_pooled = out;                       // B*D
    float* o_weights = out + (size_t)B * D;      // B*S
    float* o_attn = o_weights + (size_t)B * S;   // B*D
    float* o_topk = o_attn + (size_t)B * D;      // B*D
    float* o_tidx = o_topk + (size_t)B * D;      // B*K
    float* o_tval = o_tidx + (size_t)B * KTOP;   // B*K

    detect_mask_kernel<<<1, 256, 0, stream>>>((const unsigned char*)maskraw, mode);
    prep_kernel<<<NROWS / 256, 256, 0, stream>>>(maskraw, segq, qW1, qb1, qw2, qb2, mode, maskf, qual);
    split_w1_kernel<<<(H * D) / 256, 256, 0, stream>>>(W1, wsBh, wsBl);
    evidence_mfma_kernel<<<NROWS / 128, 256, 0, stream>>>(feats, wsBh, wsBl, b1, w2, b2, qual, maskf, comb);
    softmax_topk_kernel<<<B, 256, 0, stream>>>(comb, o_weights, o_tidx, o_tval, tidx_ws, tval_ws, denom_ws);
    pool_partial_kernel<<<dim3(NCH, B), 256, 0, stream>>>(feats, o_weights, part);
    pool_reduce_kernel<<<B, 256, 0, stream>>>(part, feats, tidx_ws, tval_ws, denom_ws, o_attn, o_topk, o_pooled);
}